// Round 1
// baseline (1160.013 us; speedup 1.0000x reference)
//
#include <hip/hip_runtime.h>

#define HW1 50176   // 224*224
#define HW2 12544   // 112*112

// ---------------- conv1: 3->64, 224x224, pad=1, +bias, relu ----------------
__global__ __launch_bounds__(256) void conv1_relu_kernel(
    const float* __restrict__ x, const float* __restrict__ w,
    const float* __restrict__ bias, float* __restrict__ out)
{
  int idx = blockIdx.x * 256 + threadIdx.x;
  if (idx >= 4 * 64 * HW1) return;
  int xw = idx % 224;
  int y  = (idx / 224) % 224;
  int o  = (idx / HW1) & 63;
  int b  = idx / (HW1 * 64);
  const float* wr = w + o * 27;
  const float* xb = x + (size_t)b * 3 * HW1;
  float acc = bias[o];
  #pragma unroll
  for (int c = 0; c < 3; ++c) {
    #pragma unroll
    for (int ky = 0; ky < 3; ++ky) {
      int yy = y + ky - 1;
      if (yy < 0 || yy >= 224) continue;
      #pragma unroll
      for (int kx = 0; kx < 3; ++kx) {
        int xx = xw + kx - 1;
        if (xx < 0 || xx >= 224) continue;
        acc += xb[(c * 224 + yy) * 224 + xx] * wr[(c * 3 + ky) * 3 + kx];
      }
    }
  }
  out[idx] = fmaxf(acc, 0.f);
}

// ---------------- BN stats: per-channel sum & sumsq --------------------------
__global__ __launch_bounds__(256) void bn_stats_kernel(
    const float* __restrict__ in, float* __restrict__ stats, int C, int HW)
{
  int c = blockIdx.y;
  float s = 0.f, s2 = 0.f;
  int stride = gridDim.x * 256;
  int start = blockIdx.x * 256 + threadIdx.x;
  for (int b = 0; b < 4; ++b) {
    const float* p = in + (size_t)(b * C + c) * HW;
    for (int i = start; i < HW; i += stride) {
      float v = p[i];
      s += v; s2 += v * v;
    }
  }
  #pragma unroll
  for (int off = 32; off > 0; off >>= 1) {
    s  += __shfl_down(s, off, 64);
    s2 += __shfl_down(s2, off, 64);
  }
  __shared__ float red[8];
  int wid = threadIdx.x >> 6, lane = threadIdx.x & 63;
  if (lane == 0) { red[wid * 2] = s; red[wid * 2 + 1] = s2; }
  __syncthreads();
  if (threadIdx.x == 0) {
    float ts = 0.f, ts2 = 0.f;
    for (int i = 0; i < 4; ++i) { ts += red[i * 2]; ts2 += red[i * 2 + 1]; }
    atomicAdd(&stats[2 * c], ts);
    atomicAdd(&stats[2 * c + 1], ts2);
  }
}

// ---------------- BN finalize: scale/shift per channel -----------------------
__global__ void bn_finalize_kernel(const float* __restrict__ stats,
                                   const float* __restrict__ g,
                                   const float* __restrict__ bb,
                                   float inv_n, float* __restrict__ ss, int C)
{
  int c = threadIdx.x;
  if (c < C) {
    float m = stats[2 * c] * inv_n;
    float v = stats[2 * c + 1] * inv_n - m * m;
    float sc = rsqrtf(v + 1e-5f) * g[c];
    ss[2 * c] = sc;
    ss[2 * c + 1] = bb[c] - m * sc;
  }
}

// ---------------- BN1 apply + 2x2 avgpool -----------------------------------
__global__ __launch_bounds__(256) void bn1_pool_kernel(
    const float* __restrict__ h1, const float* __restrict__ ss,
    float* __restrict__ out)
{
  int idx = blockIdx.x * 256 + threadIdx.x;
  if (idx >= 4 * 64 * HW2) return;
  int x = idx % 112;
  int y = (idx / 112) % 112;
  int c = (idx / HW2) & 63;
  int b = idx / (HW2 * 64);
  const float2* r0 = (const float2*)(h1 + ((size_t)((b * 64 + c) * 224 + 2 * y)) * 224);
  const float2* r1 = r0 + 112;
  float2 a = r0[x], d = r1[x];
  float avg = (a.x + a.y + d.x + d.y) * 0.25f;
  out[idx] = avg * ss[2 * c] + ss[2 * c + 1];
}

// ---------------- generic 3x3 conv, 112x112, pad=1, OB outputs/block --------
template <int OB>
__global__ __launch_bounds__(256) void conv3x3_tiled(
    const float* __restrict__ in, const float* __restrict__ w,
    const float* __restrict__ bias, float* __restrict__ out,
    int Cin, int Cout, int relu)
{
  __shared__ float in_s[8][18][18];
  int tid = threadIdx.x;
  int tx = tid & 15, ty = tid >> 4;
  int tile = blockIdx.x;
  int tx0 = (tile % 7) * 16, ty0 = (tile / 7) * 16;
  int o0 = blockIdx.y * OB;
  int b = blockIdx.z;
  float acc[OB];
  #pragma unroll
  for (int i = 0; i < OB; ++i) acc[i] = 0.f;

  for (int c0 = 0; c0 < Cin; c0 += 8) {
    __syncthreads();
    for (int t = tid; t < 8 * 324; t += 256) {
      int cc = t / 324, r2 = t % 324;
      int r = r2 / 18, col = r2 % 18;
      int yy = ty0 + r - 1, xx = tx0 + col - 1;
      float v = 0.f;
      if (yy >= 0 && yy < 112 && xx >= 0 && xx < 112)
        v = in[((size_t)(b * Cin + c0 + cc) * 112 + yy) * 112 + xx];
      in_s[cc][r][col] = v;
    }
    __syncthreads();
    #pragma unroll
    for (int cc = 0; cc < 8; ++cc) {
      float xv[9];
      #pragma unroll
      for (int ky = 0; ky < 3; ++ky)
        #pragma unroll
        for (int kx = 0; kx < 3; ++kx)
          xv[ky * 3 + kx] = in_s[cc][ty + ky][tx + kx];
      const float* wp = w + (size_t)(o0 * Cin + c0 + cc) * 9;
      #pragma unroll
      for (int oi = 0; oi < OB; ++oi) {
        #pragma unroll
        for (int k = 0; k < 9; ++k)
          acc[oi] += xv[k] * wp[(size_t)oi * Cin * 9 + k];
      }
    }
  }
  int oy = ty0 + ty, ox = tx0 + tx;
  #pragma unroll
  for (int oi = 0; oi < OB; ++oi) {
    float v = acc[oi] + bias[o0 + oi];
    if (relu) v = fmaxf(v, 0.f);
    out[((size_t)(b * Cout + o0 + oi) * 112 + oy) * 112 + ox] = v;
  }
}

// ---------------- BN2 apply, writes NCHW + NHWC ------------------------------
__global__ __launch_bounds__(256) void bn2_apply_kernel(
    const float* __restrict__ h3, const float* __restrict__ ss,
    float* __restrict__ onchw, float* __restrict__ onhwc)
{
  __shared__ float tile[16][129];
  int b = blockIdx.z, y = blockIdx.y, x0 = blockIdx.x * 16;
  int tid = threadIdx.x;
  int xx = tid & 15, cbase = tid >> 4;
  #pragma unroll
  for (int it = 0; it < 8; ++it) {
    int c = cbase + it * 16;
    size_t gi = ((size_t)((b * 128 + c) * 112 + y)) * 112 + x0 + xx;
    float v = h3[gi];
    v = v * ss[2 * c] + ss[2 * c + 1];
    onchw[gi] = v;
    tile[xx][c] = v;
  }
  __syncthreads();
  int c2 = tid & 127, xb2 = tid >> 7;
  #pragma unroll
  for (int it = 0; it < 8; ++it) {
    int xx2 = xb2 + it * 2;
    onhwc[((size_t)((b * 112 + y) * 112) + x0 + xx2) * 128 + c2] = tile[xx2][c2];
  }
}

// ---------------- deformable conv: gather + implicit GEMM --------------------
// xin: NHWC (4,112,112,128); offs: (4,18,112,112); w: (128,128,3,3); out NCHW
__global__ __launch_bounds__(256) void deform_kernel(
    const float* __restrict__ xin, const float* __restrict__ offs,
    const float* __restrict__ w, float* __restrict__ out)
{
  __shared__ int   idx_s[32][9][4];
  __shared__ float wt_s[32][9][4];
  __shared__ float x_s[36][36];
  __shared__ float w_s[36][132];

  int tid = threadIdx.x;
  int pix0 = blockIdx.x * 32;
  int b = blockIdx.y;

  for (int t = tid; t < 288; t += 256) {
    int p = t / 9, k = t % 9;
    int pix = pix0 + p;
    int i = pix / 112, j = pix % 112;
    float offx = offs[((size_t)(b * 18 + k) * 112 + i) * 112 + j];
    float offy = offs[((size_t)(b * 18 + 9 + k) * 112 + i) * 112 + j];
    float px = (float)(i + k / 3) + offx;       // (i+1) + (k/3 - 1)
    float py = (float)(j + k % 3) + offy;
    float fx = floorf(px), fy = floorf(py);
    float qltx = fminf(fmaxf(fx, 0.f), 113.f);
    float qlty = fminf(fmaxf(fy, 0.f), 113.f);
    float qrbx = fminf(fmaxf(fx + 1.f, 0.f), 113.f);
    float qrby = fminf(fmaxf(fy + 1.f, 0.f), 113.f);
    bool mx = (px < 1.f) || (px > 112.f);
    bool my = (py < 1.f) || (py > 112.f);
    float pxc = fminf(fmaxf(mx ? fx : px, 0.f), 113.f);
    float pyc = fminf(fmaxf(my ? fy : py, 0.f), 113.f);
    float glt = (1.f + (qltx - pxc)) * (1.f + (qlty - pyc));
    float grb = (1.f - (qrbx - pxc)) * (1.f - (qrby - pyc));
    float glb = (1.f + (qltx - pxc)) * (1.f - (qrby - pyc));
    float grt = (1.f - (qrbx - pxc)) * (1.f + (qlty - pyc));
    int ix0 = (int)qltx - 1, iy0 = (int)qlty - 1;
    int ix1 = (int)qrbx - 1, iy1 = (int)qrby - 1;
    bool vx0 = (ix0 >= 0 && ix0 < 112), vy0 = (iy0 >= 0 && iy0 < 112);
    bool vx1 = (ix1 >= 0 && ix1 < 112), vy1 = (iy1 >= 0 && iy1 < 112);
    idx_s[p][k][0] = (vx0 && vy0) ? ix0 * 112 + iy0 : -1;  wt_s[p][k][0] = glt;
    idx_s[p][k][1] = (vx1 && vy1) ? ix1 * 112 + iy1 : -1;  wt_s[p][k][1] = grb;
    idx_s[p][k][2] = (vx0 && vy1) ? ix0 * 112 + iy1 : -1;  wt_s[p][k][2] = glb;
    idx_s[p][k][3] = (vx1 && vy0) ? ix1 * 112 + iy0 : -1;  wt_s[p][k][3] = grt;
  }
  __syncthreads();

  float acc[4][4] = {};
  int o0 = (tid & 31) * 4;
  int p0 = (tid >> 5) * 4;
  const float* xb = xin + (size_t)b * HW2 * 128;

  for (int c0 = 0; c0 < 128; c0 += 4) {
    for (int e = tid; e < 4608; e += 256) {
      int o = e / 36, r = e % 36;
      w_s[r][o] = w[(size_t)o * 1152 + c0 * 9 + r];
    }
    for (int e = tid; e < 1152; e += 256) {
      int cc = e & 3, rem = e >> 2;
      int k = rem % 9, p = rem / 9;
      float a = 0.f;
      #pragma unroll
      for (int q = 0; q < 4; ++q) {
        int s = idx_s[p][k][q];
        if (s >= 0) a += wt_s[p][k][q] * xb[(size_t)s * 128 + c0 + cc];
      }
      x_s[cc * 9 + k][p] = a;
    }
    __syncthreads();
    #pragma unroll 6
    for (int kk = 0; kk < 36; ++kk) {
      float w0 = w_s[kk][o0], w1 = w_s[kk][o0 + 1], w2 = w_s[kk][o0 + 2], w3 = w_s[kk][o0 + 3];
      float x0v = x_s[kk][p0], x1v = x_s[kk][p0 + 1], x2v = x_s[kk][p0 + 2], x3v = x_s[kk][p0 + 3];
      acc[0][0] += w0 * x0v; acc[0][1] += w0 * x1v; acc[0][2] += w0 * x2v; acc[0][3] += w0 * x3v;
      acc[1][0] += w1 * x0v; acc[1][1] += w1 * x1v; acc[1][2] += w1 * x2v; acc[1][3] += w1 * x3v;
      acc[2][0] += w2 * x0v; acc[2][1] += w2 * x1v; acc[2][2] += w2 * x2v; acc[2][3] += w2 * x3v;
      acc[3][0] += w3 * x0v; acc[3][1] += w3 * x1v; acc[3][2] += w3 * x2v; acc[3][3] += w3 * x3v;
    }
    __syncthreads();
  }

  #pragma unroll
  for (int oi = 0; oi < 4; ++oi) {
    size_t ob = ((size_t)(b * 128 + o0 + oi)) * HW2 + pix0 + p0;
    #pragma unroll
    for (int pi = 0; pi < 4; ++pi)
      out[ob + pi] = acc[oi][pi];
  }
}

extern "C" void kernel_launch(void* const* d_in, const int* in_sizes, int n_in,
                              void* d_out, int out_size, void* d_ws, size_t ws_size,
                              hipStream_t stream)
{
  const float* x       = (const float*)d_in[0];
  const float* conv1_w = (const float*)d_in[1];
  const float* conv1_b = (const float*)d_in[2];
  const float* bn1_g   = (const float*)d_in[3];
  const float* bn1_b   = (const float*)d_in[4];
  const float* conv2_w = (const float*)d_in[5];
  const float* conv2_b = (const float*)d_in[6];
  const float* bn2_g   = (const float*)d_in[7];
  const float* bn2_b   = (const float*)d_in[8];
  const float* off_w   = (const float*)d_in[9];
  const float* off_b   = (const float*)d_in[10];
  const float* conv4_w = (const float*)d_in[11];
  float* out = (float*)d_out;
  float* ws  = (float*)d_ws;

  // workspace layout (floats), with aliasing:
  // bufA [12845056]: h1 (conv1 out); later h3 = bufA[0:6422528], h4 = bufA[6422528:]
  // bufB [3211264]:  h2 (pooled)
  // bufC [6422528]:  h4 NHWC
  // offs [903168], stats [384], ss [384]
  float* bufA  = ws;
  float* bufB  = bufA + 12845056;
  float* bufC  = bufB + 3211264;
  float* offsb = bufC + 6422528;
  float* stats = offsb + 903168;
  float* ss    = stats + 384;

  float* h1 = bufA;
  float* h2 = bufB;
  float* h3 = bufA;
  float* h4 = bufA + 6422528;
  float* h4t = bufC;

  hipMemsetAsync(stats, 0, 384 * sizeof(float), stream);

  conv1_relu_kernel<<<(4 * 64 * HW1 + 255) / 256, 256, 0, stream>>>(x, conv1_w, conv1_b, h1);
  bn_stats_kernel<<<dim3(32, 64), 256, 0, stream>>>(h1, stats, 64, HW1);
  bn_finalize_kernel<<<1, 128, 0, stream>>>(stats, bn1_g, bn1_b, 1.f / (4.f * HW1), ss, 64);
  bn1_pool_kernel<<<(4 * 64 * HW2 + 255) / 256, 256, 0, stream>>>(h1, ss, h2);
  conv3x3_tiled<16><<<dim3(49, 8, 4), 256, 0, stream>>>(h2, conv2_w, conv2_b, h3, 64, 128, 1);
  bn_stats_kernel<<<dim3(16, 128), 256, 0, stream>>>(h3, stats + 128, 128, HW2);
  bn_finalize_kernel<<<1, 128, 0, stream>>>(stats + 128, bn2_g, bn2_b, 1.f / (4.f * HW2), ss + 128, 128);
  bn2_apply_kernel<<<dim3(7, 112, 4), 256, 0, stream>>>(h3, ss + 128, h4, h4t);
  conv3x3_tiled<6><<<dim3(49, 3, 4), 256, 0, stream>>>(h4, off_w, off_b, offsb, 128, 18, 0);
  deform_kernel<<<dim3(392, 4), 256, 0, stream>>>(h4t, offsb, conv4_w, out);
}